// Round 6
// baseline (2245.632 us; speedup 1.0000x reference)
//
#include <hip/hip_runtime.h>
#include <hip/hip_bf16.h>

#define FDIM 512
#define HDIM 256
#define CDIM 64
#define KSTEPS 10
#define NPLANE 4         // 4 channel planes x 16 ch; plane = N*16*2B = 3.2MB < 4MB L2/XCD

typedef __attribute__((ext_vector_type(8))) short bf16x8;
typedef __attribute__((ext_vector_type(4))) float f32x4;

static __device__ __forceinline__ unsigned short f2bf(float f) {
  union { float f; unsigned int u; } x; x.f = f;
  unsigned int u = x.u;
  return (unsigned short)((u + 0x7fffu + ((u >> 16) & 1u)) >> 16);  // RNE
}
static __device__ __forceinline__ float bfhi2f(unsigned int u) {
  union { unsigned int u; float f; } x; x.u = u; return x.f;
}

// ---------------- weight prep: fp32 [K][N] -> bf16 transposed [N][K] -------
__global__ void prep_w(const float* __restrict__ W1, const float* __restrict__ W2,
                       unsigned short* __restrict__ W1t, unsigned short* __restrict__ W2t) {
  int i = blockIdx.x * 256 + threadIdx.x;
  if (i < FDIM * HDIM) { int k = i / HDIM, n = i % HDIM; W1t[(size_t)n * FDIM + k] = f2bf(W1[i]); }
  if (i < HDIM * CDIM) { int k = i / CDIM, n = i % CDIM; W2t[(size_t)n * HDIM + k] = f2bf(W2[i]); }
}

// ---------------- graph prep -----------------------------------------------
__global__ void deg_k(const int* __restrict__ dst, int* __restrict__ deg, int E) {
  int i = blockIdx.x * 256 + threadIdx.x;
  if (i < E) atomicAdd(&deg[dst[i]], 1);
}

// dinv, 0.9*dinv^2, sqrt(deg+1)
__global__ void dinv3_k(const int* __restrict__ deg, float* __restrict__ dinv,
                        float* __restrict__ dii9, float* __restrict__ dsq, int n) {
  int r = blockIdx.x * 256 + threadIdx.x;
  if (r < n) {
    float dp1 = (float)deg[r] + 1.0f;
    float di = rsqrtf(dp1);
    dinv[r] = di;
    dii9[r] = 0.9f * di * di;
    dsq[r] = sqrtf(dp1);
  }
}

__global__ void scan_block(const int* __restrict__ in, int* __restrict__ out,
                           int* __restrict__ bsum, int n) {
  __shared__ int tmp[1024];
  int i = blockIdx.x * 1024 + threadIdx.x;
  int v = (i < n) ? in[i] : 0;
  tmp[threadIdx.x] = v;
  __syncthreads();
  for (int off = 1; off < 1024; off <<= 1) {
    int t = (threadIdx.x >= off) ? tmp[threadIdx.x - off] : 0;
    __syncthreads();
    tmp[threadIdx.x] += t;
    __syncthreads();
  }
  if (i < n) out[i] = tmp[threadIdx.x] - v;  // exclusive
  if (threadIdx.x == 1023) bsum[blockIdx.x] = tmp[1023];
}

// parallel scan of block sums (nb <= 1024), single block
__global__ void scan_sums_par(const int* __restrict__ bsum, int* __restrict__ boff, int nb) {
  __shared__ int tmp[1024];
  int t = threadIdx.x;
  int v = (t < nb) ? bsum[t] : 0;
  tmp[t] = v;
  __syncthreads();
  for (int off = 1; off < 1024; off <<= 1) {
    int x = (t >= off) ? tmp[t - off] : 0;
    __syncthreads();
    tmp[t] += x;
    __syncthreads();
  }
  if (t < nb) boff[t] = tmp[t] - v;  // exclusive
}

__global__ void scan_add(int* __restrict__ rowptr, int* __restrict__ cursor,
                         const int* __restrict__ boff, int n, int total) {
  int i = blockIdx.x * 1024 + threadIdx.x;
  if (i < n) {
    int v = rowptr[i] + boff[blockIdx.x];
    rowptr[i] = v;
    cursor[i] = v;
  }
  if (i == 0) rowptr[n] = total;
}

// CSR fill: 4B record = src (weights folded into g-space state)
__global__ void fill3_k(const int* __restrict__ src, const int* __restrict__ dst,
                        int* __restrict__ cursor, unsigned int* __restrict__ edges, int E) {
  int i = blockIdx.x * 256 + threadIdx.x;
  if (i < E) {
    int d = dst[i];
    int p = atomicAdd(&cursor[d], 1);
    edges[p] = (unsigned int)src[i];
  }
}

// ---------------- GEMM1: h1 = relu(x @ W1 + b1), tile 64(M) x 256(N=all) ---
__global__ __launch_bounds__(256) void gemm1_k(const float* __restrict__ A,
                                               const unsigned short* __restrict__ Bt,
                                               const float* __restrict__ bias,
                                               unsigned short* __restrict__ C, int M) {
  __shared__ unsigned short Al[64][40];
  __shared__ unsigned short Bl[256][40];
  const int tid = threadIdx.x;
  const int wid = tid >> 6;
  const int lane = tid & 63;
  const int m0 = blockIdx.x * 64;
  const int srow = tid >> 2;
  const int scg = (tid & 3) * 8;
  f32x4 acc[16];
#pragma unroll
  for (int i = 0; i < 16; ++i) acc[i] = (f32x4){0.f, 0.f, 0.f, 0.f};
  for (int k0 = 0; k0 < FDIM; k0 += 32) {
    {
      const int gr = m0 + srow;
      unsigned short av[8];
      if (gr < M) {
        const float* p = A + (size_t)gr * FDIM + k0 + scg;
#pragma unroll
        for (int j = 0; j < 8; ++j) av[j] = f2bf(p[j]);
      } else {
#pragma unroll
        for (int j = 0; j < 8; ++j) av[j] = 0;
      }
      *(bf16x8*)(&Al[srow][scg]) = *(bf16x8*)av;
    }
#pragma unroll
    for (int j = 0; j < 4; ++j) {
      const int br = srow + 64 * j;
      bf16x8 v = *(const bf16x8*)(Bt + (size_t)br * FDIM + k0 + scg);
      *(bf16x8*)(&Bl[br][scg]) = v;
    }
    __syncthreads();
    bf16x8 a = *(const bf16x8*)(&Al[wid * 16 + (lane & 15)][(lane >> 4) * 8]);
#pragma unroll
    for (int nf = 0; nf < 16; ++nf) {
      bf16x8 b = *(const bf16x8*)(&Bl[nf * 16 + (lane & 15)][(lane >> 4) * 8]);
      acc[nf] = __builtin_amdgcn_mfma_f32_16x16x32_bf16(a, b, acc[nf], 0, 0, 0);
    }
    __syncthreads();
  }
#pragma unroll
  for (int nf = 0; nf < 16; ++nf) {
    const int colg = nf * 16 + (lane & 15);
    const float bb = bias[colg];
#pragma unroll
    for (int r = 0; r < 4; ++r) {
      const int rowg = m0 + wid * 16 + (lane >> 4) * 4 + r;
      if (rowg < M) {
        float v = fmaxf(acc[nf][r] + bb, 0.0f);
        C[(size_t)rowg * HDIM + colg] = f2bf(v);
      }
    }
  }
}

// ---------------- GEMM2: planes of hb0 (h0) and g0 (dinv*h0), bf16 ---------
// plane layout: X[p*M*16 + row*16 + c], p = nf (16-col group)
__global__ __launch_bounds__(256) void gemm2p_k(const unsigned short* __restrict__ A,
                                                const unsigned short* __restrict__ Bt,
                                                const float* __restrict__ bias,
                                                const float* __restrict__ dinv,
                                                unsigned short* __restrict__ Hb0,
                                                unsigned short* __restrict__ G0, int M) {
  __shared__ unsigned short Al[64][40];
  __shared__ unsigned short Bl[64][40];
  const int tid = threadIdx.x;
  const int wid = tid >> 6;
  const int lane = tid & 63;
  const int m0 = blockIdx.x * 64;
  const int srow = tid >> 2;
  const int scg = (tid & 3) * 8;
  f32x4 acc[4];
#pragma unroll
  for (int i = 0; i < 4; ++i) acc[i] = (f32x4){0.f, 0.f, 0.f, 0.f};
  for (int k0 = 0; k0 < HDIM; k0 += 32) {
    {
      const int gr = m0 + srow;
      if (gr < M) {
        bf16x8 v = *(const bf16x8*)(A + (size_t)gr * HDIM + k0 + scg);
        *(bf16x8*)(&Al[srow][scg]) = v;
      } else {
        bf16x8 z = {0, 0, 0, 0, 0, 0, 0, 0};
        *(bf16x8*)(&Al[srow][scg]) = z;
      }
    }
    {
      bf16x8 v = *(const bf16x8*)(Bt + (size_t)srow * HDIM + k0 + scg);
      *(bf16x8*)(&Bl[srow][scg]) = v;
    }
    __syncthreads();
    bf16x8 a = *(const bf16x8*)(&Al[wid * 16 + (lane & 15)][(lane >> 4) * 8]);
#pragma unroll
    for (int nf = 0; nf < 4; ++nf) {
      bf16x8 b = *(const bf16x8*)(&Bl[nf * 16 + (lane & 15)][(lane >> 4) * 8]);
      acc[nf] = __builtin_amdgcn_mfma_f32_16x16x32_bf16(a, b, acc[nf], 0, 0, 0);
    }
    __syncthreads();
  }
#pragma unroll
  for (int nf = 0; nf < 4; ++nf) {
    const float bb = bias[nf * 16 + (lane & 15)];
#pragma unroll
    for (int r = 0; r < 4; ++r) {
      const int rowg = m0 + wid * 16 + (lane >> 4) * 4 + r;
      if (rowg < M) {
        float v = acc[nf][r] + bb;
        size_t off = (size_t)nf * M * 16 + (size_t)rowg * 16 + (lane & 15);
        Hb0[off] = f2bf(v);
        G0[off] = f2bf(dinv[rowg] * v);
      }
    }
  }
}

// ---------------- APPNP plane pass ------------------------------------------
// Gathers only from plane p (3.2MB, guaranteed L2-fit). 4 lanes = 1 dst row
// (16 ch); accumulator in 4 VGPRs, no LDS, no shuffles. Edge stream + hb0 +
// out use nontemporal hints to protect the plane's L2 residency.
// g'[r] = dii9[r]*(S_r + g[r]) + 0.1*dinv[r]*h0[r]
__global__ __launch_bounds__(256) void spmv_plane_k(const int* __restrict__ rowptr,
                                                    const unsigned int* __restrict__ edges,
                                                    const float* __restrict__ dii9,
                                                    const float* __restrict__ dinv,
                                                    const unsigned short* __restrict__ hb0p,
                                                    const unsigned short* __restrict__ ginp,
                                                    unsigned short* __restrict__ goutp,
                                                    int p, int n) {
  const int tid = threadIdx.x;
  const int g = tid >> 2;        // row group 0..63
  const int cl = tid & 3;        // channel quad (4 bf16 = 8B)
  const int r = blockIdx.x * 64 + g;
  if (r >= n) return;
  const size_t base = (size_t)p * n * 16;
  const unsigned short* pin = ginp + base;
  int e = rowptr[r];
  const int e1 = rowptr[r + 1];
  f32x4 a = {0.f, 0.f, 0.f, 0.f};
  for (; e + 3 < e1; e += 4) {
    const unsigned int s0 = __builtin_nontemporal_load(edges + e);
    const unsigned int s1 = __builtin_nontemporal_load(edges + e + 1);
    const unsigned int s2 = __builtin_nontemporal_load(edges + e + 2);
    const unsigned int s3 = __builtin_nontemporal_load(edges + e + 3);
    const uint2 v0 = *(const uint2*)(pin + (size_t)s0 * 16 + cl * 4);
    const uint2 v1 = *(const uint2*)(pin + (size_t)s1 * 16 + cl * 4);
    const uint2 v2 = *(const uint2*)(pin + (size_t)s2 * 16 + cl * 4);
    const uint2 v3 = *(const uint2*)(pin + (size_t)s3 * 16 + cl * 4);
    a[0] += bfhi2f(v0.x << 16) + bfhi2f(v1.x << 16) + bfhi2f(v2.x << 16) + bfhi2f(v3.x << 16);
    a[1] += bfhi2f(v0.x & 0xffff0000u) + bfhi2f(v1.x & 0xffff0000u) +
            bfhi2f(v2.x & 0xffff0000u) + bfhi2f(v3.x & 0xffff0000u);
    a[2] += bfhi2f(v0.y << 16) + bfhi2f(v1.y << 16) + bfhi2f(v2.y << 16) + bfhi2f(v3.y << 16);
    a[3] += bfhi2f(v0.y & 0xffff0000u) + bfhi2f(v1.y & 0xffff0000u) +
            bfhi2f(v2.y & 0xffff0000u) + bfhi2f(v3.y & 0xffff0000u);
  }
  for (; e < e1; ++e) {
    const unsigned int s0 = __builtin_nontemporal_load(edges + e);
    const uint2 v0 = *(const uint2*)(pin + (size_t)s0 * 16 + cl * 4);
    a[0] += bfhi2f(v0.x << 16);
    a[1] += bfhi2f(v0.x & 0xffff0000u);
    a[2] += bfhi2f(v0.y << 16);
    a[3] += bfhi2f(v0.y & 0xffff0000u);
  }
  // finalize
  const float d9 = dii9[r];
  const float tp = 0.1f * dinv[r];
  const uint2 gs = *(const uint2*)(pin + (size_t)r * 16 + cl * 4);
  const unsigned long long hz8 =
      __builtin_nontemporal_load((const unsigned long long*)(hb0p + base + (size_t)r * 16 + cl * 4));
  const unsigned int hzx = (unsigned int)hz8;
  const unsigned int hzy = (unsigned int)(hz8 >> 32);
  const float o0 = d9 * (a[0] + bfhi2f(gs.x << 16)) + tp * bfhi2f(hzx << 16);
  const float o1 = d9 * (a[1] + bfhi2f(gs.x & 0xffff0000u)) + tp * bfhi2f(hzx & 0xffff0000u);
  const float o2 = d9 * (a[2] + bfhi2f(gs.y << 16)) + tp * bfhi2f(hzy << 16);
  const float o3 = d9 * (a[3] + bfhi2f(gs.y & 0xffff0000u)) + tp * bfhi2f(hzy & 0xffff0000u);
  unsigned long long pk =
      (unsigned long long)(((unsigned int)f2bf(o1) << 16) | f2bf(o0)) |
      ((unsigned long long)(((unsigned int)f2bf(o3) << 16) | f2bf(o2)) << 32);
  __builtin_nontemporal_store(pk, (unsigned long long*)(goutp + base + (size_t)r * 16 + cl * 4));
}

// ---------------- log_softmax (plane-layout g_K in, rescale, fp32 out) -----
__global__ __launch_bounds__(256) void logsoftmax_k(const unsigned short* __restrict__ h,
                                                    const float* __restrict__ dsq,
                                                    float* __restrict__ out, int n) {
  const int r = blockIdx.x * 4 + (threadIdx.x >> 6);
  if (r >= n) return;
  const int lane = threadIdx.x & 63;
  const int pl = lane >> 4;
  const int c = lane & 15;
  float v = bfhi2f(((unsigned int)h[(size_t)pl * n * 16 + (size_t)r * 16 + c]) << 16) * dsq[r];
  float m = v;
#pragma unroll
  for (int o = 32; o; o >>= 1) m = fmaxf(m, __shfl_xor(m, o, 64));
  float ex = expf(v - m);
  float s = ex;
#pragma unroll
  for (int o = 32; o; o >>= 1) s += __shfl_xor(s, o, 64);
  out[(size_t)r * 64 + pl * 16 + c] = v - m - logf(s);
}

extern "C" void kernel_launch(void* const* d_in, const int* in_sizes, int n_in,
                              void* d_out, int out_size, void* d_ws, size_t ws_size,
                              hipStream_t stream) {
  const float* x = (const float*)d_in[0];
  const float* W1 = (const float*)d_in[1];
  const float* b1 = (const float*)d_in[2];
  const float* W2 = (const float*)d_in[3];
  const float* b2 = (const float*)d_in[4];
  const int* ei = (const int*)d_in[5];
  const int E = in_sizes[5] / 2;
  const int N = in_sizes[0] / FDIM;
  const int* src = ei;
  const int* dst = ei + E;

  char* wp = (char*)d_ws;
  auto alloc = [&](size_t b) {
    char* p = wp;
    wp += (b + 255) & ~(size_t)255;
    return p;
  };
  unsigned short* W1t = (unsigned short*)alloc((size_t)HDIM * FDIM * 2);
  unsigned short* W2t = (unsigned short*)alloc((size_t)CDIM * HDIM * 2);
  unsigned short* h1 = (unsigned short*)alloc((size_t)N * HDIM * 2);
  unsigned short* hb0 = (unsigned short*)alloc((size_t)N * CDIM * 2);  // planes
  unsigned short* g0 = (unsigned short*)alloc((size_t)N * CDIM * 2);   // planes
  unsigned short* hA = (unsigned short*)alloc((size_t)N * CDIM * 2);   // planes
  unsigned short* hB = (unsigned short*)alloc((size_t)N * CDIM * 2);   // planes
  int* deg = (int*)alloc((size_t)N * 4);
  int* rowptr = (int*)alloc((size_t)(N + 1) * 4);
  int* cursor = (int*)alloc((size_t)N * 4);
  float* dinv = (float*)alloc((size_t)N * 4);
  float* dii9 = (float*)alloc((size_t)N * 4);
  float* dsq = (float*)alloc((size_t)N * 4);
  int* bsum = (int*)alloc(4096);
  int* boff = (int*)alloc(4096);
  unsigned int* edges = (unsigned int*)alloc((size_t)E * 4);

  // weight prep
  prep_w<<<(FDIM * HDIM + 255) / 256, 256, 0, stream>>>(W1, W2, W1t, W2t);

  // graph prep: degree -> dinv -> rowptr (scan) -> CSR fill (4B src records)
  hipMemsetAsync(deg, 0, (size_t)N * 4, stream);
  deg_k<<<(E + 255) / 256, 256, 0, stream>>>(dst, deg, E);
  dinv3_k<<<(N + 255) / 256, 256, 0, stream>>>(deg, dinv, dii9, dsq, N);
  const int nb = (N + 1023) >> 10;  // 98
  scan_block<<<nb, 1024, 0, stream>>>(deg, rowptr, bsum, N);
  scan_sums_par<<<1, 1024, 0, stream>>>(bsum, boff, nb);
  scan_add<<<nb, 1024, 0, stream>>>(rowptr, cursor, boff, N, E);
  fill3_k<<<(E + 255) / 256, 256, 0, stream>>>(src, dst, cursor, edges, E);

  // MLP
  gemm1_k<<<(N + 63) / 64, 256, 0, stream>>>(x, W1t, b1, h1, N);
  gemm2p_k<<<(N + 63) / 64, 256, 0, stream>>>(h1, W2t, b2, dinv, hb0, g0, N);

  // APPNP propagation: 10 steps x 4 plane passes (each pass L2-resident)
  const int NBLK = (N + 63) / 64;  // 1563
  const unsigned short* cur = g0;
  unsigned short* bufs[2] = {hA, hB};
  for (int t = 0; t < KSTEPS; ++t) {
    unsigned short* outb = bufs[t & 1];
    for (int p = 0; p < NPLANE; ++p)
      spmv_plane_k<<<NBLK, 256, 0, stream>>>(rowptr, edges, dii9, dinv, hb0, cur, outb, p, N);
    cur = outb;
  }

  // log_softmax (rescale g -> h) -> d_out (fp32)
  logsoftmax_k<<<(N + 3) / 4, 256, 0, stream>>>(cur, dsq, (float*)d_out, N);
}

// Round 7
// 1693.435 us; speedup vs baseline: 1.3261x; 1.3261x over previous
//
#include <hip/hip_runtime.h>
#include <hip/hip_bf16.h>

#define FDIM 512
#define HDIM 256
#define CDIM 64
#define KSTEPS 10
#define BSH 7                    // bucket = dst >> 7 (128 rows/bucket)

typedef __attribute__((ext_vector_type(8))) short bf16x8;
typedef __attribute__((ext_vector_type(4))) float f32x4;

static __device__ __forceinline__ unsigned short f2bf(float f) {
  union { float f; unsigned int u; } x; x.f = f;
  unsigned int u = x.u;
  return (unsigned short)((u + 0x7fffu + ((u >> 16) & 1u)) >> 16);  // RNE
}
static __device__ __forceinline__ float bits2f(unsigned int u) {
  union { unsigned int u; float f; } x; x.u = u; return x.f;
}

// ---------------- weight prep: fp32 [K][N] -> bf16 transposed [N][K] -------
__global__ void prep_w(const float* __restrict__ W1, const float* __restrict__ W2,
                       unsigned short* __restrict__ W1t, unsigned short* __restrict__ W2t) {
  int i = blockIdx.x * 256 + threadIdx.x;
  if (i < FDIM * HDIM) { int k = i / HDIM, n = i % HDIM; W1t[(size_t)n * FDIM + k] = f2bf(W1[i]); }
  if (i < HDIM * CDIM) { int k = i / CDIM, n = i % CDIM; W2t[(size_t)n * HDIM + k] = f2bf(W2[i]); }
}

// ---------------- graph prep -----------------------------------------------
__global__ void deg_k(const int* __restrict__ dst, int* __restrict__ deg, int E) {
  int i = blockIdx.x * 256 + threadIdx.x;
  if (i < E) atomicAdd(&deg[dst[i]], 1);
}

__global__ void dinv_k(const int* __restrict__ deg, float* __restrict__ dinv, int n) {
  int i = blockIdx.x * 256 + threadIdx.x;
  if (i < n) dinv[i] = rsqrtf((float)deg[i] + 1.0f);  // +1 self-loop
}

__global__ void scan_block(const int* __restrict__ in, int* __restrict__ out,
                           int* __restrict__ bsum, int n) {
  __shared__ int tmp[1024];
  int i = blockIdx.x * 1024 + threadIdx.x;
  int v = (i < n) ? in[i] : 0;
  tmp[threadIdx.x] = v;
  __syncthreads();
  for (int off = 1; off < 1024; off <<= 1) {
    int t = (threadIdx.x >= off) ? tmp[threadIdx.x - off] : 0;
    __syncthreads();
    tmp[threadIdx.x] += t;
    __syncthreads();
  }
  if (i < n) out[i] = tmp[threadIdx.x] - v;  // exclusive
  if (threadIdx.x == 1023) bsum[blockIdx.x] = tmp[1023];
}

__global__ void scan_sums_par(const int* __restrict__ bsum, int* __restrict__ boff, int nb) {
  __shared__ int tmp[1024];
  int t = threadIdx.x;
  int v = (t < nb) ? bsum[t] : 0;
  tmp[t] = v;
  __syncthreads();
  for (int off = 1; off < 1024; off <<= 1) {
    int x = (t >= off) ? tmp[t - off] : 0;
    __syncthreads();
    tmp[t] += x;
    __syncthreads();
  }
  if (t < nb) boff[t] = tmp[t] - v;  // exclusive
}

__global__ void scan_add(int* __restrict__ rowptr, const int* __restrict__ boff,
                         int n, int total) {
  int i = blockIdx.x * 1024 + threadIdx.x;
  if (i < n) rowptr[i] += boff[blockIdx.x];
  if (i == 0) rowptr[n] = total;
}

// per-bucket cursor init: bcur[b] = rowptr[b*128]
__global__ void bcur_init(const int* __restrict__ rowptr, int* __restrict__ bcur,
                          int nb, int n) {
  int b = blockIdx.x * 256 + threadIdx.x;
  if (b < nb) {
    int r = b << BSH;
    bcur[b] = rowptr[r < n ? r : n];
  }
}

// pass 1: scatter 16B records {src, w, dst, 0} into coarse bucket regions
__global__ void fill_p1(const int* __restrict__ src, const int* __restrict__ dst,
                        const float* __restrict__ dinv, int* __restrict__ bcur,
                        uint4* __restrict__ temp, int E) {
  int i = blockIdx.x * 256 + threadIdx.x;
  if (i < E) {
    int s = src[i], d = dst[i];
    int p = atomicAdd(&bcur[d >> BSH], 1);
    union { float f; unsigned int u; } w; w.f = dinv[s];
    temp[p] = make_uint4((unsigned int)s, w.u, (unsigned int)d, 0u);
  }
}

// pass 2: one block per bucket; LDS row cursors; writes confined to the
// bucket's own CSR window (single-L2 write absorption)
__global__ __launch_bounds__(256) void fill_p2(const int* __restrict__ rowptr,
                                               const uint4* __restrict__ temp,
                                               uint2* __restrict__ edges, int n) {
  __shared__ int lcur[1 << BSH];
  const int b = blockIdx.x;
  const int r0 = b << BSH;
  const int rend = min(r0 + (1 << BSH), n);
  const int base = rowptr[r0];
  const int end = rowptr[rend];
  const int tid = threadIdx.x;
  if (tid < (1 << BSH)) {
    int rr = r0 + tid;
    lcur[tid] = (rr < rend) ? rowptr[rr] - base : 0;
  }
  __syncthreads();
  for (int i = base + tid; i < end; i += 256) {
    uint4 rec = temp[i];
    int p = atomicAdd(&lcur[rec.z & ((1 << BSH) - 1)], 1);
    edges[base + p] = make_uint2(rec.x, rec.y);
  }
}

// ---------------- GEMM1: h1 = relu(x @ W1 + b1), tile 64(M) x 256(N=all) ---
__global__ __launch_bounds__(256) void gemm1_k(const float* __restrict__ A,
                                               const unsigned short* __restrict__ Bt,
                                               const float* __restrict__ bias,
                                               unsigned short* __restrict__ C, int M) {
  __shared__ unsigned short Al[64][40];
  __shared__ unsigned short Bl[256][40];
  const int tid = threadIdx.x;
  const int wid = tid >> 6;
  const int lane = tid & 63;
  const int m0 = blockIdx.x * 64;
  const int srow = tid >> 2;
  const int scg = (tid & 3) * 8;
  f32x4 acc[16];
#pragma unroll
  for (int i = 0; i < 16; ++i) acc[i] = (f32x4){0.f, 0.f, 0.f, 0.f};
  for (int k0 = 0; k0 < FDIM; k0 += 32) {
    {
      const int gr = m0 + srow;
      unsigned short av[8];
      if (gr < M) {
        const float* p = A + (size_t)gr * FDIM + k0 + scg;
#pragma unroll
        for (int j = 0; j < 8; ++j) av[j] = f2bf(p[j]);
      } else {
#pragma unroll
        for (int j = 0; j < 8; ++j) av[j] = 0;
      }
      *(bf16x8*)(&Al[srow][scg]) = *(bf16x8*)av;
    }
#pragma unroll
    for (int j = 0; j < 4; ++j) {
      const int br = srow + 64 * j;
      bf16x8 v = *(const bf16x8*)(Bt + (size_t)br * FDIM + k0 + scg);
      *(bf16x8*)(&Bl[br][scg]) = v;
    }
    __syncthreads();
    bf16x8 a = *(const bf16x8*)(&Al[wid * 16 + (lane & 15)][(lane >> 4) * 8]);
#pragma unroll
    for (int nf = 0; nf < 16; ++nf) {
      bf16x8 b = *(const bf16x8*)(&Bl[nf * 16 + (lane & 15)][(lane >> 4) * 8]);
      acc[nf] = __builtin_amdgcn_mfma_f32_16x16x32_bf16(a, b, acc[nf], 0, 0, 0);
    }
    __syncthreads();
  }
#pragma unroll
  for (int nf = 0; nf < 16; ++nf) {
    const int colg = nf * 16 + (lane & 15);
    const float bb = bias[colg];
#pragma unroll
    for (int r = 0; r < 4; ++r) {
      const int rowg = m0 + wid * 16 + (lane >> 4) * 4 + r;
      if (rowg < M) {
        float v = fmaxf(acc[nf][r] + bb, 0.0f);
        C[(size_t)rowg * HDIM + colg] = f2bf(v);
      }
    }
  }
}

// ---------------- GEMM2: hb0 = h1 @ W2 + b2 -> bf16, tile 64x64 ------------
__global__ __launch_bounds__(256) void gemm2_k(const unsigned short* __restrict__ A,
                                               const unsigned short* __restrict__ Bt,
                                               const float* __restrict__ bias,
                                               unsigned short* __restrict__ C, int M) {
  __shared__ unsigned short Al[64][40];
  __shared__ unsigned short Bl[64][40];
  const int tid = threadIdx.x;
  const int wid = tid >> 6;
  const int lane = tid & 63;
  const int m0 = blockIdx.x * 64;
  const int srow = tid >> 2;
  const int scg = (tid & 3) * 8;
  f32x4 acc[4];
#pragma unroll
  for (int i = 0; i < 4; ++i) acc[i] = (f32x4){0.f, 0.f, 0.f, 0.f};
  for (int k0 = 0; k0 < HDIM; k0 += 32) {
    {
      const int gr = m0 + srow;
      if (gr < M) {
        bf16x8 v = *(const bf16x8*)(A + (size_t)gr * HDIM + k0 + scg);
        *(bf16x8*)(&Al[srow][scg]) = v;
      } else {
        bf16x8 z = {0, 0, 0, 0, 0, 0, 0, 0};
        *(bf16x8*)(&Al[srow][scg]) = z;
      }
    }
    {
      bf16x8 v = *(const bf16x8*)(Bt + (size_t)srow * HDIM + k0 + scg);
      *(bf16x8*)(&Bl[srow][scg]) = v;
    }
    __syncthreads();
    bf16x8 a = *(const bf16x8*)(&Al[wid * 16 + (lane & 15)][(lane >> 4) * 8]);
#pragma unroll
    for (int nf = 0; nf < 4; ++nf) {
      bf16x8 b = *(const bf16x8*)(&Bl[nf * 16 + (lane & 15)][(lane >> 4) * 8]);
      acc[nf] = __builtin_amdgcn_mfma_f32_16x16x32_bf16(a, b, acc[nf], 0, 0, 0);
    }
    __syncthreads();
  }
#pragma unroll
  for (int nf = 0; nf < 4; ++nf) {
    const int colg = nf * 16 + (lane & 15);
    const float bb = bias[colg];
#pragma unroll
    for (int r = 0; r < 4; ++r) {
      const int rowg = m0 + wid * 16 + (lane >> 4) * 4 + r;
      if (rowg < M) C[(size_t)rowg * CDIM + colg] = f2bf(acc[nf][r] + bb);
    }
  }
}

// ---------------- APPNP step: 8 slots x 8 lanes, 16B gathers, unroll 4 -----
// one wave per dst row; lane = slot*8 + u; lane gathers 16B (8 bf16 ch) at
// channel base u*8. 32 edges in flight per wave-iteration.
// out = 0.9*di*(Sum_e w_e h_e[c] + di*h_r[c]) + 0.1*h0_r[c]
__global__ __launch_bounds__(256) void spmv_k(const int* __restrict__ rowptr,
                                              const uint2* __restrict__ edges,
                                              const float* __restrict__ dinv,
                                              const unsigned short* __restrict__ hin,
                                              const unsigned short* __restrict__ hb0,
                                              unsigned short* __restrict__ hout, int n) {
  const int tid = threadIdx.x;
  const int wid = tid >> 6;
  const int lane = tid & 63;
  const int r = blockIdx.x * 4 + wid;
  if (r >= n) return;
  const int s = lane >> 3;      // slot 0..7
  const int u = lane & 7;       // channel octet: 8 bf16 = 16B at short-offset u*8
  const int e0 = rowptr[r], e1 = rowptr[r + 1];
  float a0 = 0.f, a1 = 0.f, a2 = 0.f, a3 = 0.f;
  float a4 = 0.f, a5 = 0.f, a6 = 0.f, a7 = 0.f;
  for (int e = e0; e < e1; e += 32) {
    unsigned long long rec[4];
#pragma unroll
    for (int j = 0; j < 4; ++j) {
      const int ee = e + s + 8 * j;
      rec[j] = (ee < e1)
                   ? __builtin_nontemporal_load((const unsigned long long*)(edges + ee))
                   : 0ull;
    }
    uint4 hv[4];
#pragma unroll
    for (int j = 0; j < 4; ++j)
      hv[j] = *(const uint4*)(hin + (size_t)(unsigned int)rec[j] * 64 + u * 8);
#pragma unroll
    for (int j = 0; j < 4; ++j) {
      const float w = bits2f((unsigned int)(rec[j] >> 32));
      a0 += w * bits2f(hv[j].x << 16);
      a1 += w * bits2f(hv[j].x & 0xffff0000u);
      a2 += w * bits2f(hv[j].y << 16);
      a3 += w * bits2f(hv[j].y & 0xffff0000u);
      a4 += w * bits2f(hv[j].z << 16);
      a5 += w * bits2f(hv[j].z & 0xffff0000u);
      a6 += w * bits2f(hv[j].w << 16);
      a7 += w * bits2f(hv[j].w & 0xffff0000u);
    }
  }
  // reduce across the 8 slots (lanes u, u+8, ..., u+56)
#pragma unroll
  for (int off = 8; off <= 32; off <<= 1) {
    a0 += __shfl_xor(a0, off, 64);
    a1 += __shfl_xor(a1, off, 64);
    a2 += __shfl_xor(a2, off, 64);
    a3 += __shfl_xor(a3, off, 64);
    a4 += __shfl_xor(a4, off, 64);
    a5 += __shfl_xor(a5, off, 64);
    a6 += __shfl_xor(a6, off, 64);
    a7 += __shfl_xor(a7, off, 64);
  }
  if (s == 0) {  // lanes 0..7 finalize 8 channels each
    const float di = dinv[r];
    const uint4 hs = *(const uint4*)(hin + (size_t)r * 64 + u * 8);
    const uint4 hz = *(const uint4*)(hb0 + (size_t)r * 64 + u * 8);
    const float o0 = 0.9f * di * (a0 + di * bits2f(hs.x << 16)) + 0.1f * bits2f(hz.x << 16);
    const float o1 = 0.9f * di * (a1 + di * bits2f(hs.x & 0xffff0000u)) + 0.1f * bits2f(hz.x & 0xffff0000u);
    const float o2 = 0.9f * di * (a2 + di * bits2f(hs.y << 16)) + 0.1f * bits2f(hz.y << 16);
    const float o3 = 0.9f * di * (a3 + di * bits2f(hs.y & 0xffff0000u)) + 0.1f * bits2f(hz.y & 0xffff0000u);
    const float o4 = 0.9f * di * (a4 + di * bits2f(hs.z << 16)) + 0.1f * bits2f(hz.z << 16);
    const float o5 = 0.9f * di * (a5 + di * bits2f(hs.z & 0xffff0000u)) + 0.1f * bits2f(hz.z & 0xffff0000u);
    const float o6 = 0.9f * di * (a6 + di * bits2f(hs.w << 16)) + 0.1f * bits2f(hz.w << 16);
    const float o7 = 0.9f * di * (a7 + di * bits2f(hs.w & 0xffff0000u)) + 0.1f * bits2f(hz.w & 0xffff0000u);
    uint4 pk;
    pk.x = ((unsigned int)f2bf(o1) << 16) | f2bf(o0);
    pk.y = ((unsigned int)f2bf(o3) << 16) | f2bf(o2);
    pk.z = ((unsigned int)f2bf(o5) << 16) | f2bf(o4);
    pk.w = ((unsigned int)f2bf(o7) << 16) | f2bf(o6);
    *(uint4*)(hout + (size_t)r * 64 + u * 8) = pk;
  }
}

// ---------------- log_softmax over 64 classes (bf16 in, fp32 out) ----------
__global__ __launch_bounds__(256) void logsoftmax_k(const unsigned short* __restrict__ h,
                                                    float* __restrict__ out, int n) {
  const int r = blockIdx.x * 4 + (threadIdx.x >> 6);
  if (r >= n) return;
  const int lane = threadIdx.x & 63;
  float v = bits2f(((unsigned int)h[(size_t)r * 64 + lane]) << 16);
  float m = v;
#pragma unroll
  for (int o = 32; o; o >>= 1) m = fmaxf(m, __shfl_xor(m, o, 64));
  float ex = expf(v - m);
  float s = ex;
#pragma unroll
  for (int o = 32; o; o >>= 1) s += __shfl_xor(s, o, 64);
  out[(size_t)r * 64 + lane] = v - m - logf(s);
}

extern "C" void kernel_launch(void* const* d_in, const int* in_sizes, int n_in,
                              void* d_out, int out_size, void* d_ws, size_t ws_size,
                              hipStream_t stream) {
  const float* x = (const float*)d_in[0];
  const float* W1 = (const float*)d_in[1];
  const float* b1 = (const float*)d_in[2];
  const float* W2 = (const float*)d_in[3];
  const float* b2 = (const float*)d_in[4];
  const int* ei = (const int*)d_in[5];
  const int E = in_sizes[5] / 2;
  const int N = in_sizes[0] / FDIM;
  const int* src = ei;
  const int* dst = ei + E;

  const int NB = (N + (1 << BSH) - 1) >> BSH;  // 782 buckets

  char* wp = (char*)d_ws;
  auto alloc = [&](size_t b) {
    char* p = wp;
    wp += (b + 255) & ~(size_t)255;
    return p;
  };
  unsigned short* W1t = (unsigned short*)alloc((size_t)HDIM * FDIM * 2);
  unsigned short* W2t = (unsigned short*)alloc((size_t)CDIM * HDIM * 2);
  unsigned short* h1 = (unsigned short*)alloc((size_t)N * HDIM * 2);  // 51.2MB
  unsigned short* hb0 = (unsigned short*)alloc((size_t)N * CDIM * 2);
  unsigned short* hA = (unsigned short*)alloc((size_t)N * CDIM * 2);
  unsigned short* hB = (unsigned short*)alloc((size_t)N * CDIM * 2);
  int* deg = (int*)alloc((size_t)N * 4);
  int* rowptr = (int*)alloc((size_t)(N + 1) * 4);
  int* bcur = (int*)alloc((size_t)(NB + 1) * 4);
  float* dinv = (float*)alloc((size_t)N * 4);
  int* bsum = (int*)alloc(4096);
  int* boff = (int*)alloc(4096);
  uint2* edges = (uint2*)alloc((size_t)E * 8);
  uint4* temp = (uint4*)h1;  // alias: E*16B == N*HDIM*2B; used only after gemm2

  // weight prep + degree/scan chain (independent of GEMMs)
  prep_w<<<(FDIM * HDIM + 255) / 256, 256, 0, stream>>>(W1, W2, W1t, W2t);
  hipMemsetAsync(deg, 0, (size_t)N * 4, stream);
  deg_k<<<(E + 255) / 256, 256, 0, stream>>>(dst, deg, E);
  dinv_k<<<(N + 255) / 256, 256, 0, stream>>>(deg, dinv, N);
  const int nb = (N + 1023) >> 10;  // 98
  scan_block<<<nb, 1024, 0, stream>>>(deg, rowptr, bsum, N);
  scan_sums_par<<<1, 1024, 0, stream>>>(bsum, boff, nb);
  scan_add<<<nb, 1024, 0, stream>>>(rowptr, boff, N, E);
  bcur_init<<<(NB + 255) / 256, 256, 0, stream>>>(rowptr, bcur, NB, N);

  // MLP (h1 consumed before temp aliases it)
  gemm1_k<<<(N + 63) / 64, 256, 0, stream>>>(x, W1t, b1, h1, N);
  gemm2_k<<<(N + 63) / 64, 256, 0, stream>>>(h1, W2t, b2, hb0, N);

  // CSR fill: coarse-binned scatter, then per-bucket LDS-cursor scatter
  fill_p1<<<(E + 255) / 256, 256, 0, stream>>>(src, dst, dinv, bcur, temp, E);
  fill_p2<<<NB, 256, 0, stream>>>(rowptr, temp, edges, N);

  // APPNP propagation (10 steps, ping-pong, bf16 state)
  const unsigned short* cur = hb0;
  unsigned short* bufs[2] = {hA, hB};
  for (int t = 0; t < KSTEPS; ++t) {
    unsigned short* outb = bufs[t & 1];
    spmv_k<<<(N + 3) / 4, 256, 0, stream>>>(rowptr, edges, dinv, cur, hb0, outb, N);
    cur = outb;
  }

  // log_softmax -> d_out (fp32)
  logsoftmax_k<<<(N + 3) / 4, 256, 0, stream>>>(cur, (float*)d_out, N);
}

// Round 8
// 1061.761 us; speedup vs baseline: 2.1150x; 1.5949x over previous
//
#include <hip/hip_runtime.h>
#include <hip/hip_bf16.h>

#define FDIM 512
#define HDIM 256
#define CDIM 64
#define KSTEPS 10

typedef __attribute__((ext_vector_type(8))) short bf16x8;
typedef __attribute__((ext_vector_type(4))) float f32x4;

static __device__ __forceinline__ unsigned short f2bf(float f) {
  union { float f; unsigned int u; } x; x.f = f;
  unsigned int u = x.u;
  return (unsigned short)((u + 0x7fffu + ((u >> 16) & 1u)) >> 16);  // RNE
}
static __device__ __forceinline__ float bits2f(unsigned int u) {
  union { unsigned int u; float f; } x; x.u = u; return x.f;
}

// ---------------- weight prep: fp32 [K][N] -> bf16 transposed [N][K] -------
__global__ void prep_w(const float* __restrict__ W1, const float* __restrict__ W2,
                       unsigned short* __restrict__ W1t, unsigned short* __restrict__ W2t) {
  int i = blockIdx.x * 256 + threadIdx.x;
  if (i < FDIM * HDIM) { int k = i / HDIM, n = i % HDIM; W1t[(size_t)n * FDIM + k] = f2bf(W1[i]); }
  if (i < HDIM * CDIM) { int k = i / CDIM, n = i % CDIM; W2t[(size_t)n * HDIM + k] = f2bf(W2[i]); }
}

// ---------------- graph prep: XCD-partitioned by dst range -----------------
// range(d) = min(7, floor(d * rinv)), rinv = 8/N. blockIdx&7 -> XCD (perf
// heuristic only): each range's counters/CSR slice stay in one XCD's L2.
__global__ __launch_bounds__(256) void deg_x(const int* __restrict__ dst,
                                             int* __restrict__ deg, int E, float rinv) {
  const int rng = blockIdx.x & 7;
  const int g = (blockIdx.x >> 3) * 256 + threadIdx.x;
  const int stride = (gridDim.x >> 3) * 256;
  for (int i = g; i < E; i += stride) {
    const int d = dst[i];
    const int r = min(7, (int)((float)d * rinv));
    if (r == rng) atomicAdd(&deg[d], 1);
  }
}

__global__ void dinv_k(const int* __restrict__ deg, float* __restrict__ dinv, int n) {
  int i = blockIdx.x * 256 + threadIdx.x;
  if (i < n) dinv[i] = rsqrtf((float)deg[i] + 1.0f);  // +1 self-loop
}

__global__ void scan_block(const int* __restrict__ in, int* __restrict__ out,
                           int* __restrict__ bsum, int n) {
  __shared__ int tmp[1024];
  int i = blockIdx.x * 1024 + threadIdx.x;
  int v = (i < n) ? in[i] : 0;
  tmp[threadIdx.x] = v;
  __syncthreads();
  for (int off = 1; off < 1024; off <<= 1) {
    int t = (threadIdx.x >= off) ? tmp[threadIdx.x - off] : 0;
    __syncthreads();
    tmp[threadIdx.x] += t;
    __syncthreads();
  }
  if (i < n) out[i] = tmp[threadIdx.x] - v;  // exclusive
  if (threadIdx.x == 1023) bsum[blockIdx.x] = tmp[1023];
}

__global__ void scan_sums_par(const int* __restrict__ bsum, int* __restrict__ boff, int nb) {
  __shared__ int tmp[1024];
  int t = threadIdx.x;
  int v = (t < nb) ? bsum[t] : 0;
  tmp[t] = v;
  __syncthreads();
  for (int off = 1; off < 1024; off <<= 1) {
    int x = (t >= off) ? tmp[t - off] : 0;
    __syncthreads();
    tmp[t] += x;
    __syncthreads();
  }
  if (t < nb) boff[t] = tmp[t] - v;  // exclusive
}

__global__ void scan_add(int* __restrict__ rowptr, int* __restrict__ cursor,
                         const int* __restrict__ boff, int n, int total) {
  int i = blockIdx.x * 1024 + threadIdx.x;
  if (i < n) {
    int v = rowptr[i] + boff[blockIdx.x];
    rowptr[i] = v;
    cursor[i] = v;
  }
  if (i == 0) rowptr[n] = total;
}

// XCD-partitioned CSR fill: 8B record {src, bits(dinv[src])}; each range's
// scatter window (~3.2MB) and cursors (~50KB) stay XCD-local.
__global__ __launch_bounds__(256) void fill_x(const int* __restrict__ src,
                                              const int* __restrict__ dst,
                                              const float* __restrict__ dinv,
                                              int* __restrict__ cursor,
                                              uint2* __restrict__ edges, int E, float rinv) {
  const int rng = blockIdx.x & 7;
  const int g = (blockIdx.x >> 3) * 256 + threadIdx.x;
  const int stride = (gridDim.x >> 3) * 256;
  for (int i = g; i < E; i += stride) {
    const int d = dst[i];
    const int r = min(7, (int)((float)d * rinv));
    if (r == rng) {
      const int s = src[i];
      const int p = atomicAdd(&cursor[d], 1);
      union { float f; unsigned int u; } w; w.f = dinv[s];
      edges[p] = make_uint2((unsigned int)s, w.u);
    }
  }
}

// ---------------- GEMM1: h1 = relu(x @ W1 + b1), tile 64(M) x 256(N=all) ---
__global__ __launch_bounds__(256) void gemm1_k(const float* __restrict__ A,
                                               const unsigned short* __restrict__ Bt,
                                               const float* __restrict__ bias,
                                               unsigned short* __restrict__ C, int M) {
  __shared__ unsigned short Al[64][40];
  __shared__ unsigned short Bl[256][40];
  const int tid = threadIdx.x;
  const int wid = tid >> 6;
  const int lane = tid & 63;
  const int m0 = blockIdx.x * 64;
  const int srow = tid >> 2;
  const int scg = (tid & 3) * 8;
  f32x4 acc[16];
#pragma unroll
  for (int i = 0; i < 16; ++i) acc[i] = (f32x4){0.f, 0.f, 0.f, 0.f};
  for (int k0 = 0; k0 < FDIM; k0 += 32) {
    {
      const int gr = m0 + srow;
      unsigned short av[8];
      if (gr < M) {
        const float* p = A + (size_t)gr * FDIM + k0 + scg;
#pragma unroll
        for (int j = 0; j < 8; ++j) av[j] = f2bf(p[j]);
      } else {
#pragma unroll
        for (int j = 0; j < 8; ++j) av[j] = 0;
      }
      *(bf16x8*)(&Al[srow][scg]) = *(bf16x8*)av;
    }
#pragma unroll
    for (int j = 0; j < 4; ++j) {
      const int br = srow + 64 * j;
      bf16x8 v = *(const bf16x8*)(Bt + (size_t)br * FDIM + k0 + scg);
      *(bf16x8*)(&Bl[br][scg]) = v;
    }
    __syncthreads();
    bf16x8 a = *(const bf16x8*)(&Al[wid * 16 + (lane & 15)][(lane >> 4) * 8]);
#pragma unroll
    for (int nf = 0; nf < 16; ++nf) {
      bf16x8 b = *(const bf16x8*)(&Bl[nf * 16 + (lane & 15)][(lane >> 4) * 8]);
      acc[nf] = __builtin_amdgcn_mfma_f32_16x16x32_bf16(a, b, acc[nf], 0, 0, 0);
    }
    __syncthreads();
  }
#pragma unroll
  for (int nf = 0; nf < 16; ++nf) {
    const int colg = nf * 16 + (lane & 15);
    const float bb = bias[colg];
#pragma unroll
    for (int r = 0; r < 4; ++r) {
      const int rowg = m0 + wid * 16 + (lane >> 4) * 4 + r;
      if (rowg < M) {
        float v = fmaxf(acc[nf][r] + bb, 0.0f);
        C[(size_t)rowg * HDIM + colg] = f2bf(v);
      }
    }
  }
}

// ---------------- GEMM2: hb0 = h1 @ W2 + b2 -> bf16, tile 64x64 ------------
__global__ __launch_bounds__(256) void gemm2_k(const unsigned short* __restrict__ A,
                                               const unsigned short* __restrict__ Bt,
                                               const float* __restrict__ bias,
                                               unsigned short* __restrict__ C, int M) {
  __shared__ unsigned short Al[64][40];
  __shared__ unsigned short Bl[64][40];
  const int tid = threadIdx.x;
  const int wid = tid >> 6;
  const int lane = tid & 63;
  const int m0 = blockIdx.x * 64;
  const int srow = tid >> 2;
  const int scg = (tid & 3) * 8;
  f32x4 acc[4];
#pragma unroll
  for (int i = 0; i < 4; ++i) acc[i] = (f32x4){0.f, 0.f, 0.f, 0.f};
  for (int k0 = 0; k0 < HDIM; k0 += 32) {
    {
      const int gr = m0 + srow;
      if (gr < M) {
        bf16x8 v = *(const bf16x8*)(A + (size_t)gr * HDIM + k0 + scg);
        *(bf16x8*)(&Al[srow][scg]) = v;
      } else {
        bf16x8 z = {0, 0, 0, 0, 0, 0, 0, 0};
        *(bf16x8*)(&Al[srow][scg]) = z;
      }
    }
    {
      bf16x8 v = *(const bf16x8*)(Bt + (size_t)srow * HDIM + k0 + scg);
      *(bf16x8*)(&Bl[srow][scg]) = v;
    }
    __syncthreads();
    bf16x8 a = *(const bf16x8*)(&Al[wid * 16 + (lane & 15)][(lane >> 4) * 8]);
#pragma unroll
    for (int nf = 0; nf < 4; ++nf) {
      bf16x8 b = *(const bf16x8*)(&Bl[nf * 16 + (lane & 15)][(lane >> 4) * 8]);
      acc[nf] = __builtin_amdgcn_mfma_f32_16x16x32_bf16(a, b, acc[nf], 0, 0, 0);
    }
    __syncthreads();
  }
#pragma unroll
  for (int nf = 0; nf < 4; ++nf) {
    const int colg = nf * 16 + (lane & 15);
    const float bb = bias[colg];
#pragma unroll
    for (int r = 0; r < 4; ++r) {
      const int rowg = m0 + wid * 16 + (lane >> 4) * 4 + r;
      if (rowg < M) C[(size_t)rowg * CDIM + colg] = f2bf(acc[nf][r] + bb);
    }
  }
}

// ---------------- APPNP step: 8 slots x 8 lanes, 16B gathers, unroll 4 -----
__global__ __launch_bounds__(256) void spmv_k(const int* __restrict__ rowptr,
                                              const uint2* __restrict__ edges,
                                              const float* __restrict__ dinv,
                                              const unsigned short* __restrict__ hin,
                                              const unsigned short* __restrict__ hb0,
                                              unsigned short* __restrict__ hout, int n) {
  const int tid = threadIdx.x;
  const int wid = tid >> 6;
  const int lane = tid & 63;
  const int r = blockIdx.x * 4 + wid;
  if (r >= n) return;
  const int s = lane >> 3;      // slot 0..7
  const int u = lane & 7;       // channel octet: 8 bf16 = 16B at short-offset u*8
  const int e0 = rowptr[r], e1 = rowptr[r + 1];
  float a0 = 0.f, a1 = 0.f, a2 = 0.f, a3 = 0.f;
  float a4 = 0.f, a5 = 0.f, a6 = 0.f, a7 = 0.f;
  for (int e = e0; e < e1; e += 32) {
    unsigned long long rec[4];
#pragma unroll
    for (int j = 0; j < 4; ++j) {
      const int ee = e + s + 8 * j;
      rec[j] = (ee < e1)
                   ? __builtin_nontemporal_load((const unsigned long long*)(edges + ee))
                   : 0ull;
    }
    uint4 hv[4];
#pragma unroll
    for (int j = 0; j < 4; ++j)
      hv[j] = *(const uint4*)(hin + (size_t)(unsigned int)rec[j] * 64 + u * 8);
#pragma unroll
    for (int j = 0; j < 4; ++j) {
      const float w = bits2f((unsigned int)(rec[j] >> 32));
      a0 += w * bits2f(hv[j].x << 16);
      a1 += w * bits2f(hv[j].x & 0xffff0000u);
      a2 += w * bits2f(hv[j].y << 16);
      a3 += w * bits2f(hv[j].y & 0xffff0000u);
      a4 += w * bits2f(hv[j].z << 16);
      a5 += w * bits2f(hv[j].z & 0xffff0000u);
      a6 += w * bits2f(hv[j].w << 16);
      a7 += w * bits2f(hv[j].w & 0xffff0000u);
    }
  }
#pragma unroll
  for (int off = 8; off <= 32; off <<= 1) {
    a0 += __shfl_xor(a0, off, 64);
    a1 += __shfl_xor(a1, off, 64);
    a2 += __shfl_xor(a2, off, 64);
    a3 += __shfl_xor(a3, off, 64);
    a4 += __shfl_xor(a4, off, 64);
    a5 += __shfl_xor(a5, off, 64);
    a6 += __shfl_xor(a6, off, 64);
    a7 += __shfl_xor(a7, off, 64);
  }
  if (s == 0) {  // lanes 0..7 finalize 8 channels each
    const float di = dinv[r];
    const uint4 hs = *(const uint4*)(hin + (size_t)r * 64 + u * 8);
    const uint4 hz = *(const uint4*)(hb0 + (size_t)r * 64 + u * 8);
    const float o0 = 0.9f * di * (a0 + di * bits2f(hs.x << 16)) + 0.1f * bits2f(hz.x << 16);
    const float o1 = 0.9f * di * (a1 + di * bits2f(hs.x & 0xffff0000u)) + 0.1f * bits2f(hz.x & 0xffff0000u);
    const float o2 = 0.9f * di * (a2 + di * bits2f(hs.y << 16)) + 0.1f * bits2f(hz.y << 16);
    const float o3 = 0.9f * di * (a3 + di * bits2f(hs.y & 0xffff0000u)) + 0.1f * bits2f(hz.y & 0xffff0000u);
    const float o4 = 0.9f * di * (a4 + di * bits2f(hs.z << 16)) + 0.1f * bits2f(hz.z << 16);
    const float o5 = 0.9f * di * (a5 + di * bits2f(hs.z & 0xffff0000u)) + 0.1f * bits2f(hz.z & 0xffff0000u);
    const float o6 = 0.9f * di * (a6 + di * bits2f(hs.w << 16)) + 0.1f * bits2f(hz.w << 16);
    const float o7 = 0.9f * di * (a7 + di * bits2f(hs.w & 0xffff0000u)) + 0.1f * bits2f(hz.w & 0xffff0000u);
    uint4 pk;
    pk.x = ((unsigned int)f2bf(o1) << 16) | f2bf(o0);
    pk.y = ((unsigned int)f2bf(o3) << 16) | f2bf(o2);
    pk.z = ((unsigned int)f2bf(o5) << 16) | f2bf(o4);
    pk.w = ((unsigned int)f2bf(o7) << 16) | f2bf(o6);
    *(uint4*)(hout + (size_t)r * 64 + u * 8) = pk;
  }
}

// ---------------- log_softmax over 64 classes (bf16 in, fp32 out) ----------
__global__ __launch_bounds__(256) void logsoftmax_k(const unsigned short* __restrict__ h,
                                                    float* __restrict__ out, int n) {
  const int r = blockIdx.x * 4 + (threadIdx.x >> 6);
  if (r >= n) return;
  const int lane = threadIdx.x & 63;
  float v = bits2f(((unsigned int)h[(size_t)r * 64 + lane]) << 16);
  float m = v;
#pragma unroll
  for (int o = 32; o; o >>= 1) m = fmaxf(m, __shfl_xor(m, o, 64));
  float ex = expf(v - m);
  float s = ex;
#pragma unroll
  for (int o = 32; o; o >>= 1) s += __shfl_xor(s, o, 64);
  out[(size_t)r * 64 + lane] = v - m - logf(s);
}

extern "C" void kernel_launch(void* const* d_in, const int* in_sizes, int n_in,
                              void* d_out, int out_size, void* d_ws, size_t ws_size,
                              hipStream_t stream) {
  const float* x = (const float*)d_in[0];
  const float* W1 = (const float*)d_in[1];
  const float* b1 = (const float*)d_in[2];
  const float* W2 = (const float*)d_in[3];
  const float* b2 = (const float*)d_in[4];
  const int* ei = (const int*)d_in[5];
  const int E = in_sizes[5] / 2;
  const int N = in_sizes[0] / FDIM;
  const int* src = ei;
  const int* dst = ei + E;
  const float rinv = 8.0f / (float)N;

  char* wp = (char*)d_ws;
  auto alloc = [&](size_t b) {
    char* p = wp;
    wp += (b + 255) & ~(size_t)255;
    return p;
  };
  unsigned short* W1t = (unsigned short*)alloc((size_t)HDIM * FDIM * 2);
  unsigned short* W2t = (unsigned short*)alloc((size_t)CDIM * HDIM * 2);
  unsigned short* h1 = (unsigned short*)alloc((size_t)N * HDIM * 2);
  unsigned short* hb0 = (unsigned short*)alloc((size_t)N * CDIM * 2);
  unsigned short* hA = (unsigned short*)alloc((size_t)N * CDIM * 2);
  unsigned short* hB = (unsigned short*)alloc((size_t)N * CDIM * 2);
  int* deg = (int*)alloc((size_t)N * 4);
  int* rowptr = (int*)alloc((size_t)(N + 1) * 4);
  int* cursor = (int*)alloc((size_t)N * 4);
  float* dinv = (float*)alloc((size_t)N * 4);
  int* bsum = (int*)alloc(4096);
  int* boff = (int*)alloc(4096);
  uint2* edges = (uint2*)alloc((size_t)E * 8);

  // weight prep
  prep_w<<<(FDIM * HDIM + 255) / 256, 256, 0, stream>>>(W1, W2, W1t, W2t);

  // graph prep: XCD-partitioned degree -> dinv -> scan -> XCD-partitioned fill
  hipMemsetAsync(deg, 0, (size_t)N * 4, stream);
  deg_x<<<2048, 256, 0, stream>>>(dst, deg, E, rinv);
  dinv_k<<<(N + 255) / 256, 256, 0, stream>>>(deg, dinv, N);
  const int nb = (N + 1023) >> 10;  // 98
  scan_block<<<nb, 1024, 0, stream>>>(deg, rowptr, bsum, N);
  scan_sums_par<<<1, 1024, 0, stream>>>(bsum, boff, nb);
  scan_add<<<nb, 1024, 0, stream>>>(rowptr, cursor, boff, N, E);
  fill_x<<<2048, 256, 0, stream>>>(src, dst, dinv, cursor, edges, E, rinv);

  // MLP
  gemm1_k<<<(N + 63) / 64, 256, 0, stream>>>(x, W1t, b1, h1, N);
  gemm2_k<<<(N + 63) / 64, 256, 0, stream>>>(h1, W2t, b2, hb0, N);

  // APPNP propagation (10 steps, ping-pong, bf16 state)
  const unsigned short* cur = hb0;
  unsigned short* bufs[2] = {hA, hB};
  for (int t = 0; t < KSTEPS; ++t) {
    unsigned short* outb = bufs[t & 1];
    spmv_k<<<(N + 3) / 4, 256, 0, stream>>>(rowptr, edges, dinv, cur, hb0, outb, N);
    cur = outb;
  }

  // log_softmax -> d_out (fp32)
  logsoftmax_k<<<(N + 3) / 4, 256, 0, stream>>>(cur, (float*)d_out, N);
}

// Round 9
// 1024.437 us; speedup vs baseline: 2.1921x; 1.0364x over previous
//
#include <hip/hip_runtime.h>
#include <hip/hip_bf16.h>

#define FDIM 512
#define HDIM 256
#define CDIM 64
#define KSTEPS 10

typedef __attribute__((ext_vector_type(8))) short bf16x8;
typedef __attribute__((ext_vector_type(4))) float f32x4;
typedef __attribute__((ext_vector_type(2))) float f32x2;

static __device__ __forceinline__ unsigned short f2bf(float f) {
  union { float f; unsigned int u; } x; x.f = f;
  unsigned int u = x.u;
  return (unsigned short)((u + 0x7fffu + ((u >> 16) & 1u)) >> 16);  // RNE
}
static __device__ __forceinline__ float bits2f(unsigned int u) {
  union { unsigned int u; float f; } x; x.u = u; return x.f;
}

// ---------------- weight prep: fp32 [K][N] -> bf16 transposed [N][K] -------
__global__ void prep_w(const float* __restrict__ W1, const float* __restrict__ W2,
                       unsigned short* __restrict__ W1t, unsigned short* __restrict__ W2t) {
  int i = blockIdx.x * 256 + threadIdx.x;
  if (i < FDIM * HDIM) { int k = i / HDIM, n = i % HDIM; W1t[(size_t)n * FDIM + k] = f2bf(W1[i]); }
  if (i < HDIM * CDIM) { int k = i / CDIM, n = i % CDIM; W2t[(size_t)n * HDIM + k] = f2bf(W2[i]); }
}

// ---------------- graph prep: XCD-partitioned by dst range -----------------
__global__ __launch_bounds__(256) void deg_x(const int* __restrict__ dst,
                                             int* __restrict__ deg, int E, float rinv) {
  const int rng = blockIdx.x & 7;
  const int g = (blockIdx.x >> 3) * 256 + threadIdx.x;
  const int stride = (gridDim.x >> 3) * 256;
  for (int i = g; i < E; i += stride) {
    const int d = __builtin_nontemporal_load(dst + i);
    const int r = min(7, (int)((float)d * rinv));
    if (r == rng) atomicAdd(&deg[d], 1);
  }
}

__global__ void dinv_k(const int* __restrict__ deg, float* __restrict__ dinv, int n) {
  int i = blockIdx.x * 256 + threadIdx.x;
  if (i < n) dinv[i] = rsqrtf((float)deg[i] + 1.0f);  // +1 self-loop
}

__global__ void scan_block(const int* __restrict__ in, int* __restrict__ out,
                           int* __restrict__ bsum, int n) {
  __shared__ int tmp[1024];
  int i = blockIdx.x * 1024 + threadIdx.x;
  int v = (i < n) ? in[i] : 0;
  tmp[threadIdx.x] = v;
  __syncthreads();
  for (int off = 1; off < 1024; off <<= 1) {
    int t = (threadIdx.x >= off) ? tmp[threadIdx.x - off] : 0;
    __syncthreads();
    tmp[threadIdx.x] += t;
    __syncthreads();
  }
  if (i < n) out[i] = tmp[threadIdx.x] - v;  // exclusive
  if (threadIdx.x == 1023) bsum[blockIdx.x] = tmp[1023];
}

__global__ void scan_sums_par(const int* __restrict__ bsum, int* __restrict__ boff, int nb) {
  __shared__ int tmp[1024];
  int t = threadIdx.x;
  int v = (t < nb) ? bsum[t] : 0;
  tmp[t] = v;
  __syncthreads();
  for (int off = 1; off < 1024; off <<= 1) {
    int x = (t >= off) ? tmp[t - off] : 0;
    __syncthreads();
    tmp[t] += x;
    __syncthreads();
  }
  if (t < nb) boff[t] = tmp[t] - v;  // exclusive
}

__global__ void scan_add(int* __restrict__ rowptr, int* __restrict__ cursor,
                         const int* __restrict__ boff, int n, int total) {
  int i = blockIdx.x * 1024 + threadIdx.x;
  if (i < n) {
    int v = rowptr[i] + boff[blockIdx.x];
    rowptr[i] = v;
    cursor[i] = v;
  }
  if (i == 0) rowptr[n] = total;
}

// XCD-partitioned CSR fill: 8B record {src, bits(dinv[src])}
__global__ __launch_bounds__(256) void fill_x(const int* __restrict__ src,
                                              const int* __restrict__ dst,
                                              const float* __restrict__ dinv,
                                              int* __restrict__ cursor,
                                              uint2* __restrict__ edges, int E, float rinv) {
  const int rng = blockIdx.x & 7;
  const int g = (blockIdx.x >> 3) * 256 + threadIdx.x;
  const int stride = (gridDim.x >> 3) * 256;
  for (int i = g; i < E; i += stride) {
    const int d = __builtin_nontemporal_load(dst + i);
    const int r = min(7, (int)((float)d * rinv));
    if (r == rng) {
      const int s = __builtin_nontemporal_load(src + i);
      const int p = atomicAdd(&cursor[d], 1);
      union { float f; unsigned int u; } w; w.f = dinv[s];
      edges[p] = make_uint2((unsigned int)s, w.u);
    }
  }
}

// ---------------- GEMM1: h1 = relu(x @ W1 + b1), tile 64(M) x 256(N=all) ---
__global__ __launch_bounds__(256) void gemm1_k(const float* __restrict__ A,
                                               const unsigned short* __restrict__ Bt,
                                               const float* __restrict__ bias,
                                               unsigned short* __restrict__ C, int M) {
  __shared__ unsigned short Al[64][40];
  __shared__ unsigned short Bl[256][40];
  const int tid = threadIdx.x;
  const int wid = tid >> 6;
  const int lane = tid & 63;
  const int m0 = blockIdx.x * 64;
  const int srow = tid >> 2;
  const int scg = (tid & 3) * 8;
  f32x4 acc[16];
#pragma unroll
  for (int i = 0; i < 16; ++i) acc[i] = (f32x4){0.f, 0.f, 0.f, 0.f};
  for (int k0 = 0; k0 < FDIM; k0 += 32) {
    {
      const int gr = m0 + srow;
      unsigned short av[8];
      if (gr < M) {
        const float* p = A + (size_t)gr * FDIM + k0 + scg;
#pragma unroll
        for (int j = 0; j < 8; ++j) av[j] = f2bf(p[j]);
      } else {
#pragma unroll
        for (int j = 0; j < 8; ++j) av[j] = 0;
      }
      *(bf16x8*)(&Al[srow][scg]) = *(bf16x8*)av;
    }
#pragma unroll
    for (int j = 0; j < 4; ++j) {
      const int br = srow + 64 * j;
      bf16x8 v = *(const bf16x8*)(Bt + (size_t)br * FDIM + k0 + scg);
      *(bf16x8*)(&Bl[br][scg]) = v;
    }
    __syncthreads();
    bf16x8 a = *(const bf16x8*)(&Al[wid * 16 + (lane & 15)][(lane >> 4) * 8]);
#pragma unroll
    for (int nf = 0; nf < 16; ++nf) {
      bf16x8 b = *(const bf16x8*)(&Bl[nf * 16 + (lane & 15)][(lane >> 4) * 8]);
      acc[nf] = __builtin_amdgcn_mfma_f32_16x16x32_bf16(a, b, acc[nf], 0, 0, 0);
    }
    __syncthreads();
  }
#pragma unroll
  for (int nf = 0; nf < 16; ++nf) {
    const int colg = nf * 16 + (lane & 15);
    const float bb = bias[colg];
#pragma unroll
    for (int r = 0; r < 4; ++r) {
      const int rowg = m0 + wid * 16 + (lane >> 4) * 4 + r;
      if (rowg < M) {
        float v = fmaxf(acc[nf][r] + bb, 0.0f);
        C[(size_t)rowg * HDIM + colg] = f2bf(v);
      }
    }
  }
}

// ---------------- GEMM2: hb0 = h1 @ W2 + b2 -> bf16, tile 64x64 ------------
__global__ __launch_bounds__(256) void gemm2_k(const unsigned short* __restrict__ A,
                                               const unsigned short* __restrict__ Bt,
                                               const float* __restrict__ bias,
                                               unsigned short* __restrict__ C, int M) {
  __shared__ unsigned short Al[64][40];
  __shared__ unsigned short Bl[64][40];
  const int tid = threadIdx.x;
  const int wid = tid >> 6;
  const int lane = tid & 63;
  const int m0 = blockIdx.x * 64;
  const int srow = tid >> 2;
  const int scg = (tid & 3) * 8;
  f32x4 acc[4];
#pragma unroll
  for (int i = 0; i < 4; ++i) acc[i] = (f32x4){0.f, 0.f, 0.f, 0.f};
  for (int k0 = 0; k0 < HDIM; k0 += 32) {
    {
      const int gr = m0 + srow;
      if (gr < M) {
        bf16x8 v = *(const bf16x8*)(A + (size_t)gr * HDIM + k0 + scg);
        *(bf16x8*)(&Al[srow][scg]) = v;
      } else {
        bf16x8 z = {0, 0, 0, 0, 0, 0, 0, 0};
        *(bf16x8*)(&Al[srow][scg]) = z;
      }
    }
    {
      bf16x8 v = *(const bf16x8*)(Bt + (size_t)srow * HDIM + k0 + scg);
      *(bf16x8*)(&Bl[srow][scg]) = v;
    }
    __syncthreads();
    bf16x8 a = *(const bf16x8*)(&Al[wid * 16 + (lane & 15)][(lane >> 4) * 8]);
#pragma unroll
    for (int nf = 0; nf < 4; ++nf) {
      bf16x8 b = *(const bf16x8*)(&Bl[nf * 16 + (lane & 15)][(lane >> 4) * 8]);
      acc[nf] = __builtin_amdgcn_mfma_f32_16x16x32_bf16(a, b, acc[nf], 0, 0, 0);
    }
    __syncthreads();
  }
#pragma unroll
  for (int nf = 0; nf < 4; ++nf) {
    const int colg = nf * 16 + (lane & 15);
    const float bb = bias[colg];
#pragma unroll
    for (int r = 0; r < 4; ++r) {
      const int rowg = m0 + wid * 16 + (lane >> 4) * 4 + r;
      if (rowg < M) C[(size_t)rowg * CDIM + colg] = f2bf(acc[nf][r] + bb);
    }
  }
}

// ---------------- bf16 h0 -> fp8 e4m3 initial state ------------------------
__global__ __launch_bounds__(256) void cvt8_k(const unsigned short* __restrict__ hb0,
                                              unsigned char* __restrict__ g0, long total8) {
  long i = (long)blockIdx.x * 256 + threadIdx.x;   // one uint2 (8 ch) per thread
  if (i >= total8) return;
  const uint4 hv = *(const uint4*)(hb0 + i * 8);
  float o0 = bits2f(hv.x << 16), o1 = bits2f(hv.x & 0xffff0000u);
  float o2 = bits2f(hv.y << 16), o3 = bits2f(hv.y & 0xffff0000u);
  float o4 = bits2f(hv.z << 16), o5 = bits2f(hv.z & 0xffff0000u);
  float o6 = bits2f(hv.w << 16), o7 = bits2f(hv.w & 0xffff0000u);
  int lo = 0, hi = 0;
  lo = __builtin_amdgcn_cvt_pk_fp8_f32(o0, o1, lo, false);
  lo = __builtin_amdgcn_cvt_pk_fp8_f32(o2, o3, lo, true);
  hi = __builtin_amdgcn_cvt_pk_fp8_f32(o4, o5, hi, false);
  hi = __builtin_amdgcn_cvt_pk_fp8_f32(o6, o7, hi, true);
  *(uint2*)(g0 + i * 8) = make_uint2((unsigned int)lo, (unsigned int)hi);
}

// ---------------- APPNP step: fp8 state, 8 slots x 8 lanes, 8B gathers -----
// row = 64 B (one line). out = 0.9*di*(Sum w_e h_e + di*h_r) + 0.1*h0_r
// LAST=0: write fp8 state; LAST=1: write bf16 row for log_softmax.
template <int LAST>
__global__ __launch_bounds__(256) void spmv8_k(const int* __restrict__ rowptr,
                                               const uint2* __restrict__ edges,
                                               const float* __restrict__ dinv,
                                               const unsigned char* __restrict__ hin,
                                               const unsigned short* __restrict__ hb0,
                                               void* __restrict__ hout, int n) {
  const int tid = threadIdx.x;
  const int wid = tid >> 6;
  const int lane = tid & 63;
  const int r = blockIdx.x * 4 + wid;
  if (r >= n) return;
  const int s = lane >> 3;      // slot 0..7
  const int u = lane & 7;       // channel octet: 8 fp8 = 8B
  const int e0 = rowptr[r], e1 = rowptr[r + 1];
  float a0 = 0.f, a1 = 0.f, a2 = 0.f, a3 = 0.f;
  float a4 = 0.f, a5 = 0.f, a6 = 0.f, a7 = 0.f;
  for (int e = e0; e < e1; e += 32) {
    unsigned long long rec[4];
#pragma unroll
    for (int j = 0; j < 4; ++j) {
      const int ee = e + s + 8 * j;
      rec[j] = (ee < e1)
                   ? __builtin_nontemporal_load((const unsigned long long*)(edges + ee))
                   : 0ull;
    }
    uint2 hv[4];
#pragma unroll
    for (int j = 0; j < 4; ++j)
      hv[j] = *(const uint2*)(hin + (size_t)(unsigned int)rec[j] * 64 + u * 8);
#pragma unroll
    for (int j = 0; j < 4; ++j) {
      const float w = bits2f((unsigned int)(rec[j] >> 32));
      const f32x2 p0 = __builtin_amdgcn_cvt_pk_f32_fp8((int)hv[j].x, false);
      const f32x2 p1 = __builtin_amdgcn_cvt_pk_f32_fp8((int)hv[j].x, true);
      const f32x2 p2 = __builtin_amdgcn_cvt_pk_f32_fp8((int)hv[j].y, false);
      const f32x2 p3 = __builtin_amdgcn_cvt_pk_f32_fp8((int)hv[j].y, true);
      a0 += w * p0.x; a1 += w * p0.y;
      a2 += w * p1.x; a3 += w * p1.y;
      a4 += w * p2.x; a5 += w * p2.y;
      a6 += w * p3.x; a7 += w * p3.y;
    }
  }
#pragma unroll
  for (int off = 8; off <= 32; off <<= 1) {
    a0 += __shfl_xor(a0, off, 64);
    a1 += __shfl_xor(a1, off, 64);
    a2 += __shfl_xor(a2, off, 64);
    a3 += __shfl_xor(a3, off, 64);
    a4 += __shfl_xor(a4, off, 64);
    a5 += __shfl_xor(a5, off, 64);
    a6 += __shfl_xor(a6, off, 64);
    a7 += __shfl_xor(a7, off, 64);
  }
  if (s == 0) {  // lanes 0..7 finalize 8 channels each
    const float di = dinv[r];
    const uint2 hs = *(const uint2*)(hin + (size_t)r * 64 + u * 8);
    const uint4 hz = *(const uint4*)(hb0 + (size_t)r * 64 + u * 8);
    const f32x2 s0 = __builtin_amdgcn_cvt_pk_f32_fp8((int)hs.x, false);
    const f32x2 s1 = __builtin_amdgcn_cvt_pk_f32_fp8((int)hs.x, true);
    const f32x2 s2 = __builtin_amdgcn_cvt_pk_f32_fp8((int)hs.y, false);
    const f32x2 s3 = __builtin_amdgcn_cvt_pk_f32_fp8((int)hs.y, true);
    const float o0 = 0.9f * di * (a0 + di * s0.x) + 0.1f * bits2f(hz.x << 16);
    const float o1 = 0.9f * di * (a1 + di * s0.y) + 0.1f * bits2f(hz.x & 0xffff0000u);
    const float o2 = 0.9f * di * (a2 + di * s1.x) + 0.1f * bits2f(hz.y << 16);
    const float o3 = 0.9f * di * (a3 + di * s1.y) + 0.1f * bits2f(hz.y & 0xffff0000u);
    const float o4 = 0.9f * di * (a4 + di * s2.x) + 0.1f * bits2f(hz.z << 16);
    const float o5 = 0.9f * di * (a5 + di * s2.y) + 0.1f * bits2f(hz.z & 0xffff0000u);
    const float o6 = 0.9f * di * (a6 + di * s3.x) + 0.1f * bits2f(hz.w << 16);
    const float o7 = 0.9f * di * (a7 + di * s3.y) + 0.1f * bits2f(hz.w & 0xffff0000u);
    if (LAST) {
      uint4 pk;
      pk.x = ((unsigned int)f2bf(o1) << 16) | f2bf(o0);
      pk.y = ((unsigned int)f2bf(o3) << 16) | f2bf(o2);
      pk.z = ((unsigned int)f2bf(o5) << 16) | f2bf(o4);
      pk.w = ((unsigned int)f2bf(o7) << 16) | f2bf(o6);
      *(uint4*)((unsigned short*)hout + (size_t)r * 64 + u * 8) = pk;
    } else {
      int lo = 0, hi = 0;
      lo = __builtin_amdgcn_cvt_pk_fp8_f32(o0, o1, lo, false);
      lo = __builtin_amdgcn_cvt_pk_fp8_f32(o2, o3, lo, true);
      hi = __builtin_amdgcn_cvt_pk_fp8_f32(o4, o5, hi, false);
      hi = __builtin_amdgcn_cvt_pk_fp8_f32(o6, o7, hi, true);
      *(uint2*)((unsigned char*)hout + (size_t)r * 64 + u * 8) =
          make_uint2((unsigned int)lo, (unsigned int)hi);
    }
  }
}

// ---------------- log_softmax over 64 classes (bf16 in, fp32 out) ----------
__global__ __launch_bounds__(256) void logsoftmax_k(const unsigned short* __restrict__ h,
                                                    float* __restrict__ out, int n) {
  const int r = blockIdx.x * 4 + (threadIdx.x >> 6);
  if (r >= n) return;
  const int lane = threadIdx.x & 63;
  float v = bits2f(((unsigned int)h[(size_t)r * 64 + lane]) << 16);
  float m = v;
#pragma unroll
  for (int o = 32; o; o >>= 1) m = fmaxf(m, __shfl_xor(m, o, 64));
  float ex = expf(v - m);
  float s = ex;
#pragma unroll
  for (int o = 32; o; o >>= 1) s += __shfl_xor(s, o, 64);
  out[(size_t)r * 64 + lane] = v - m - logf(s);
}

extern "C" void kernel_launch(void* const* d_in, const int* in_sizes, int n_in,
                              void* d_out, int out_size, void* d_ws, size_t ws_size,
                              hipStream_t stream) {
  const float* x = (const float*)d_in[0];
  const float* W1 = (const float*)d_in[1];
  const float* b1 = (const float*)d_in[2];
  const float* W2 = (const float*)d_in[3];
  const float* b2 = (const float*)d_in[4];
  const int* ei = (const int*)d_in[5];
  const int E = in_sizes[5] / 2;
  const int N = in_sizes[0] / FDIM;
  const int* src = ei;
  const int* dst = ei + E;
  const float rinv = 8.0f / (float)N;

  char* wp = (char*)d_ws;
  auto alloc = [&](size_t b) {
    char* p = wp;
    wp += (b + 255) & ~(size_t)255;
    return p;
  };
  unsigned short* W1t = (unsigned short*)alloc((size_t)HDIM * FDIM * 2);
  unsigned short* W2t = (unsigned short*)alloc((size_t)CDIM * HDIM * 2);
  unsigned short* h1 = (unsigned short*)alloc((size_t)N * HDIM * 2);
  unsigned short* hb0 = (unsigned short*)alloc((size_t)N * CDIM * 2);
  unsigned short* hF = (unsigned short*)alloc((size_t)N * CDIM * 2);
  unsigned char* g0 = (unsigned char*)alloc((size_t)N * CDIM);
  unsigned char* gA = (unsigned char*)alloc((size_t)N * CDIM);
  unsigned char* gB = (unsigned char*)alloc((size_t)N * CDIM);
  int* deg = (int*)alloc((size_t)N * 4);
  int* rowptr = (int*)alloc((size_t)(N + 1) * 4);
  int* cursor = (int*)alloc((size_t)N * 4);
  float* dinv = (float*)alloc((size_t)N * 4);
  int* bsum = (int*)alloc(4096);
  int* boff = (int*)alloc(4096);
  uint2* edges = (uint2*)alloc((size_t)E * 8);

  // weight prep
  prep_w<<<(FDIM * HDIM + 255) / 256, 256, 0, stream>>>(W1, W2, W1t, W2t);

  // graph prep: XCD-partitioned degree -> dinv -> scan -> XCD-partitioned fill
  hipMemsetAsync(deg, 0, (size_t)N * 4, stream);
  deg_x<<<2048, 256, 0, stream>>>(dst, deg, E, rinv);
  dinv_k<<<(N + 255) / 256, 256, 0, stream>>>(deg, dinv, N);
  const int nb = (N + 1023) >> 10;  // 98
  scan_block<<<nb, 1024, 0, stream>>>(deg, rowptr, bsum, N);
  scan_sums_par<<<1, 1024, 0, stream>>>(bsum, boff, nb);
  scan_add<<<nb, 1024, 0, stream>>>(rowptr, cursor, boff, N, E);
  fill_x<<<2048, 256, 0, stream>>>(src, dst, dinv, cursor, edges, E, rinv);

  // MLP
  gemm1_k<<<(N + 63) / 64, 256, 0, stream>>>(x, W1t, b1, h1, N);
  gemm2_k<<<(N + 63) / 64, 256, 0, stream>>>(h1, W2t, b2, hb0, N);
  const long total8 = (long)N * CDIM / 8;
  cvt8_k<<<(int)((total8 + 255) / 256), 256, 0, stream>>>(hb0, g0, total8);

  // APPNP propagation: fp8 state steps 0..8, final step writes bf16
  const unsigned char* cur = g0;
  unsigned char* bufs[2] = {gA, gB};
  for (int t = 0; t < KSTEPS - 1; ++t) {
    unsigned char* outb = bufs[t & 1];
    spmv8_k<0><<<(N + 3) / 4, 256, 0, stream>>>(rowptr, edges, dinv, cur, hb0, outb, N);
    cur = outb;
  }
  spmv8_k<1><<<(N + 3) / 4, 256, 0, stream>>>(rowptr, edges, dinv, cur, hb0, hF, N);

  // log_softmax -> d_out (fp32)
  logsoftmax_k<<<(N + 3) / 4, 256, 0, stream>>>(hF, (float*)d_out, N);
}